// Round 3
// baseline (550.101 us; speedup 1.0000x reference)
//
#include <hip/hip_runtime.h>
#include <hip/hip_bf16.h>
#include <math.h>

#define B_ 4
#define S_ 2048
#define H_ 768
#define M_ (B_*S_)                 // 8192 rows
#define MN ((size_t)M_*(size_t)H_) // 6291456
#define HH (H_*H_)                 // 589824
#define SS ((size_t)S_*(size_t)S_)
#define SH ((size_t)S_*(size_t)H_)

typedef __bf16 bf16_t;
typedef __bf16 bf16x8 __attribute__((ext_vector_type(8)));
typedef __bf16 bf16x4 __attribute__((ext_vector_type(4)));
typedef float  f32x4  __attribute__((ext_vector_type(4)));
typedef unsigned short u16;
typedef u16 u16x4 __attribute__((ext_vector_type(4)));

typedef __attribute__((address_space(3))) void       lds_void_t;
typedef __attribute__((address_space(1))) const void gvoid_t;

__device__ __forceinline__ float b2f(u16 u){ unsigned x = (unsigned)u << 16; float f; __builtin_memcpy(&f,&x,4); return f; }
__device__ __forceinline__ u16 f2b(float f){ bf16_t h = (bf16_t)f; u16 u; __builtin_memcpy(&u,&h,2); return u; }

// ---------------- block reduction helper (blockDim == 256) ----------------
template<bool MAXOP>
__device__ __forceinline__ float blockReduce(float v, float* s){
  #pragma unroll
  for (int o = 32; o; o >>= 1){
    float t = __shfl_xor(v, o);
    v = MAXOP ? fmaxf(v, t) : (v + t);
  }
  int lane = threadIdx.x & 63, w = threadIdx.x >> 6;
  if (lane == 0) s[w] = v;
  __syncthreads();
  float r = s[0];
  #pragma unroll
  for (int i = 1; i < 4; i++) r = MAXOP ? fmaxf(r, s[i]) : (r + s[i]);
  __syncthreads();
  return r;
}

__device__ __forceinline__ float waveMax(float v){
  #pragma unroll
  for (int o = 1; o < 64; o <<= 1) v = fmaxf(v, __shfl_xor(v, o));
  return v;
}

// ---------------- weight conversion fp32 -> bf16 (x4 vectorized) ----------------
struct W18 { const float* p[18]; };

__global__ __launch_bounds__(256) void conv_weights(W18 w, bf16_t* __restrict__ out){
  int m = blockIdx.y;
  int i = (blockIdx.x * 256 + threadIdx.x) * 4;   // grid.x*1024 == HH exactly
  f32x4 v = *(const f32x4*)(w.p[m] + i);
  bf16x4 o; o[0]=(bf16_t)v[0]; o[1]=(bf16_t)v[1]; o[2]=(bf16_t)v[2]; o[3]=(bf16_t)v[3];
  *(bf16x4*)(out + (size_t)m * HH + i) = o;
}

// ---------------- LayerNorm: bf16 out ----------------
__global__ __launch_bounds__(256) void ln_kernel(const float* __restrict__ x,
                                                 const float* __restrict__ w,
                                                 const float* __restrict__ b,
                                                 bf16_t* __restrict__ outb){
  __shared__ float red[4];
  int row = blockIdx.x, t = threadIdx.x;
  size_t base = (size_t)row * H_;
  float v[3]; float sum = 0.f, sq = 0.f;
  #pragma unroll
  for (int i = 0; i < 3; i++){
    v[i] = x[base + t + i*256];
    sum += v[i]; sq += v[i]*v[i];
  }
  sum = blockReduce<false>(sum, red);
  sq  = blockReduce<false>(sq,  red);
  float mu  = sum * (1.f/H_);
  float var = sq  * (1.f/H_) - mu*mu;
  float rstd = rsqrtf(var + 1e-5f);
  #pragma unroll
  for (int i = 0; i < 3; i++){
    int j = t + i*256;
    outb[base+j] = (bf16_t)((v[i]-mu)*rstd*w[j] + b[j]);
  }
}

// ======================================================================
// 256x256 / BK=64 / 8-wave / 8-phase GEMM: C = A * B^T (bf16 in/out)
// counted vmcnt, XOR-swizzled LDS reads with pre-swizzled global source.
// ======================================================================
__global__ __launch_bounds__(512, 2) void gemm256(const bf16_t* __restrict__ A,
                                                  const bf16_t* __restrict__ Bm,
                                                  bf16_t* __restrict__ C,
                                                  int M, int N, int K,
                                                  long sA, long sB, long sC,
                                                  float scale0, float scale1, float scale2,
                                                  const float* __restrict__ bias0, int causal){
  extern __shared__ char smem[];   // 128 KiB: A[2][256*64] | B[2][256*64]
  char* Abase = smem;
  char* Bbase = smem + 65536;

  // bijective XCD swizzle over flat id (nwg % 8 == 0 for all our grids)
  int gx = gridDim.x, gy = gridDim.y;
  int nwg = gx * gy * gridDim.z;
  int id  = (blockIdx.z * gy + blockIdx.y) * gx + blockIdx.x;
  int sid = (id & 7) * (nwg >> 3) + (id >> 3);
  int bx  = sid % gx;
  int by  = (sid / gx) % gy;
  int z   = sid / (gx * gy);

  A  += (size_t)z * sA;
  Bm += (size_t)z * sB;
  C  += (size_t)z * sC;
  float scale = (z==0) ? scale0 : (z==1) ? scale1 : scale2;
  const float* bias = (z==0) ? bias0 : nullptr;

  int row0 = by * 256, col0 = bx * 256;
  if (causal && col0 > row0) return;

  int tid  = threadIdx.x;
  int lane = tid & 63, wid = tid >> 6;
  int wm = wid >> 2, wn = wid & 3;        // 2x4 wave grid; wave block 128x64
  int lr = lane & 15, kg = lane >> 4;

  int NT = K >> 6;                         // BK = 64

  // staging geometry: per half (128 rows x 64 cols bf16 = 16 KiB), thread
  // handles chunks {tid, tid+512}: row r1, r1+64, 16B chunk cb (0..7).
  int r1 = tid >> 3, cb = tid & 7;
  int ecol = (cb ^ (r1 & 7)) * 8;          // swizzled source col (bf16 elems)

  auto stageA = [&](int buf, int h, int kt){
    const bf16_t* src = A + (size_t)(row0 + h*128 + r1) * K + kt*64 + ecol;
    char* dst = Abase + buf*32768 + (h*128 + r1)*128 + cb*16;
    __builtin_amdgcn_global_load_lds((gvoid_t*)src,          (lds_void_t*)dst,          16, 0, 0);
    __builtin_amdgcn_global_load_lds((gvoid_t*)(src + (size_t)64*K), (lds_void_t*)(dst + 64*128), 16, 0, 0);
  };
  auto stageB = [&](int buf, int h, int kt){
    const bf16_t* src = Bm + (size_t)(col0 + h*128 + r1) * K + kt*64 + ecol;
    char* dst = Bbase + buf*32768 + (h*128 + r1)*128 + cb*16;
    __builtin_amdgcn_global_load_lds((gvoid_t*)src,          (lds_void_t*)dst,          16, 0, 0);
    __builtin_amdgcn_global_load_lds((gvoid_t*)(src + (size_t)64*K), (lds_void_t*)(dst + 64*128), 16, 0, 0);
  };
  auto rdA = [&](int buf, int r, int s) -> bf16x8 {
    int off = r*128 + ((s*64 + kg*16) ^ ((r & 7) << 4));
    return *(const bf16x8*)(Abase + buf*32768 + off);
  };
  auto rdB = [&](int buf, int r, int s) -> bf16x8 {
    int off = r*128 + ((s*64 + kg*16) ^ ((r & 7) << 4));
    return *(const bf16x8*)(Bbase + buf*32768 + off);
  };

  f32x4 acc[8][4] = {};

  // prologue: tile0 (A+B) + tile1 A halves; wait tile0, keep 4 in flight
  stageA(0,0,0); stageA(0,1,0); stageB(0,0,0); stageB(0,1,0);
  if (NT > 1){ stageA(1,0,1); stageA(1,1,1); }
  asm volatile("s_waitcnt vmcnt(4)" ::: "memory");
  __builtin_amdgcn_s_barrier();

  bf16x8 a0[8], a1[8], b0[4], b1[4];
  for (int t = 0; t < NT; ++t){
    int buf = t & 1, nb = buf ^ 1;
    // ---- phase 0: read k0 frags; stage B(t+1) low ----
    #pragma unroll
    for (int m = 0; m < 8; m++) a0[m] = rdA(buf, wm*128 + m*16 + lr, 0);
    #pragma unroll
    for (int n = 0; n < 4; n++) b0[n] = rdB(buf, wn*64 + n*16 + lr, 0);
    if (t + 1 < NT) stageB(nb, 0, t+1);
    __builtin_amdgcn_s_barrier();
    __builtin_amdgcn_s_setprio(1);
    #pragma unroll
    for (int m = 0; m < 8; m++){
      acc[m][0] = __builtin_amdgcn_mfma_f32_16x16x32_bf16(a0[m], b0[0], acc[m][0], 0,0,0);
      acc[m][1] = __builtin_amdgcn_mfma_f32_16x16x32_bf16(a0[m], b0[1], acc[m][1], 0,0,0);
    }
    __builtin_amdgcn_s_setprio(0);
    __builtin_amdgcn_s_barrier();
    // ---- phase 1: read k1 frags; stage B(t+1) high ----
    #pragma unroll
    for (int m = 0; m < 8; m++) a1[m] = rdA(buf, wm*128 + m*16 + lr, 1);
    #pragma unroll
    for (int n = 0; n < 4; n++) b1[n] = rdB(buf, wn*64 + n*16 + lr, 1);
    if (t + 1 < NT) stageB(nb, 1, t+1);
    __builtin_amdgcn_s_barrier();
    __builtin_amdgcn_s_setprio(1);
    #pragma unroll
    for (int m = 0; m < 8; m++){
      acc[m][2] = __builtin_amdgcn_mfma_f32_16x16x32_bf16(a0[m], b0[2], acc[m][2], 0,0,0);
      acc[m][3] = __builtin_amdgcn_mfma_f32_16x16x32_bf16(a0[m], b0[3], acc[m][3], 0,0,0);
    }
    __builtin_amdgcn_s_setprio(0);
    asm volatile("s_waitcnt lgkmcnt(0)" ::: "memory");   // buf fully consumed by all waves
    __builtin_amdgcn_s_barrier();
    // ---- phase 2: stage A(t+2) low (into buf: safe now) ----
    if (t + 2 < NT) stageA(buf, 0, t+2);
    __builtin_amdgcn_s_barrier();
    __builtin_amdgcn_s_setprio(1);
    #pragma unroll
    for (int m = 0; m < 8; m++){
      acc[m][0] = __builtin_amdgcn_mfma_f32_16x16x32_bf16(a1[m], b1[0], acc[m][0], 0,0,0);
      acc[m][1] = __builtin_amdgcn_mfma_f32_16x16x32_bf16(a1[m], b1[1], acc[m][1], 0,0,0);
    }
    __builtin_amdgcn_s_setprio(0);
    __builtin_amdgcn_s_barrier();
    // ---- phase 3: stage A(t+2) high; MFMA; tile checkpoint ----
    if (t + 2 < NT) stageA(buf, 1, t+2);
    __builtin_amdgcn_s_barrier();
    __builtin_amdgcn_s_setprio(1);
    #pragma unroll
    for (int m = 0; m < 8; m++){
      acc[m][2] = __builtin_amdgcn_mfma_f32_16x16x32_bf16(a1[m], b1[2], acc[m][2], 0,0,0);
      acc[m][3] = __builtin_amdgcn_mfma_f32_16x16x32_bf16(a1[m], b1[3], acc[m][3], 0,0,0);
    }
    __builtin_amdgcn_s_setprio(0);
    if (t + 1 < NT){
      if (t + 2 < NT) asm volatile("s_waitcnt vmcnt(4)" ::: "memory");
      else            asm volatile("s_waitcnt vmcnt(0)" ::: "memory");
      __builtin_amdgcn_s_barrier();
    }
  }

  // epilogue: C/D layout col=lane&15, row=(lane>>4)*4+reg
  #pragma unroll
  for (int m = 0; m < 8; m++){
    int rb = row0 + wm*128 + m*16 + kg*4;
    #pragma unroll
    for (int n = 0; n < 4; n++){
      int cc = col0 + wn*64 + n*16 + lr;
      float bv = bias ? bias[cc] : 0.f;
      #pragma unroll
      for (int r = 0; r < 4; r++)
        C[(size_t)(rb + r)*N + cc] = (bf16_t)(acc[m][n][r]*scale + bv);
    }
  }
}

// ---------------- 128x128 GEMM (kept for PV) ----------------
__global__ __launch_bounds__(256) void gemm_bt(const bf16_t* __restrict__ A,
                                               const bf16_t* __restrict__ Bm,
                                               bf16_t* __restrict__ C,
                                               int M, int N, int K,
                                               long sA, long sB, long sC,
                                               float scale0, float scale1, float scale2,
                                               const float* __restrict__ bias0, int cmode){
  int gx = gridDim.x, gy = gridDim.y;
  int nwg = gx * gy * gridDim.z;
  int id  = (blockIdx.z * gy + blockIdx.y) * gx + blockIdx.x;
  int sid = (id & 7) * (nwg >> 3) + (id >> 3);
  int bx  = sid % gx;
  int by  = (sid / gx) % gy;
  int z   = sid / (gx * gy);

  A  += (size_t)z * sA;
  Bm += (size_t)z * sB;
  C  += (size_t)z * sC;
  float scale = (z==0) ? scale0 : (z==1) ? scale1 : scale2;
  const float* bias = (z==0) ? bias0 : nullptr;

  int row0 = by * 128, col0 = bx * 128;
  if (cmode == 1 && col0 > row0) return;

  __shared__ bf16_t As[2][128*32];
  __shared__ bf16_t Bs[2][128*32];

  int tid  = threadIdx.x;
  int lane = tid & 63;
  int wave = tid >> 6;
  int wm = wave >> 1, wn = wave & 1;
  int lr = lane & 15, kg = lane >> 4;

  f32x4 acc[4][4] = {};
  int NT = K >> 5;
  if (cmode == 2) { int lim = (row0 + 128) >> 5; NT = NT < lim ? NT : lim; }

  auto stage = [&](int buf, int kt){
    int kk = kt * 32;
    #pragma unroll
    for (int i = 0; i < 2; i++){
      int c  = tid + i*256;
      int r  = c >> 2;
      int c8 = (c & 3) * 8;
      __builtin_amdgcn_global_load_lds((gvoid_t*)(A  + (size_t)(row0 + r)*K + kk + c8),
                                       (lds_void_t*)(&As[buf][c*8]), 16, 0, 0);
      __builtin_amdgcn_global_load_lds((gvoid_t*)(Bm + (size_t)(col0 + r)*K + kk + c8),
                                       (lds_void_t*)(&Bs[buf][c*8]), 16, 0, 0);
    }
  };

  stage(0, 0);
  __syncthreads();
  int buf = 0;
  for (int kt = 0; kt < NT; ++kt){
    if (kt + 1 < NT) stage(buf ^ 1, kt + 1);
    bf16x8 af[4], bfr[4];
    #pragma unroll
    for (int m = 0; m < 4; m++)
      af[m] = *reinterpret_cast<const bf16x8*>(&As[buf][(wm*64 + m*16 + lr)*32 + kg*8]);
    #pragma unroll
    for (int n = 0; n < 4; n++)
      bfr[n] = *reinterpret_cast<const bf16x8*>(&Bs[buf][(wn*64 + n*16 + lr)*32 + kg*8]);
    #pragma unroll
    for (int m = 0; m < 4; m++)
      #pragma unroll
      for (int n = 0; n < 4; n++)
        acc[m][n] = __builtin_amdgcn_mfma_f32_16x16x32_bf16(af[m], bfr[n], acc[m][n], 0, 0, 0);
    __syncthreads();
    buf ^= 1;
  }

  #pragma unroll
  for (int m = 0; m < 4; m++){
    int rb = row0 + wm*64 + m*16 + kg*4;
    #pragma unroll
    for (int n = 0; n < 4; n++){
      int cc = col0 + wn*64 + n*16 + lr;
      float bv = bias ? bias[cc] : 0.f;
      #pragma unroll
      for (int r = 0; r < 4; r++)
        C[(size_t)(rb + r)*N + cc] = (bf16_t)(acc[m][n][r]*scale + bv);
    }
  }
}

// ---------------- gate branch: wave-per-row, vectorized ----------------
// mode 0: rope -> outb ; mode 1: plain -> outb ; mode 2: +resid -> outf ; mode 3: relu -> outb
__global__ __launch_bounds__(256) void gate_kernel(const bf16_t* __restrict__ inp,
                                                   const bf16_t* __restrict__ c3,
                                                   const float* __restrict__ cosT,
                                                   const float* __restrict__ sinT,
                                                   const float* __restrict__ resid,
                                                   float* __restrict__ outf,
                                                   bf16_t* __restrict__ outb,
                                                   int mode){
  int wid = threadIdx.x >> 6, l = threadIdx.x & 63;
  int row = blockIdx.x * 4 + wid;
  size_t base = (size_t)row * H_ + l*12;

  float iv[12], cv[12], mv[12], gv[12];
  #pragma unroll
  for (int i = 0; i < 3; i++){
    u16x4 a = *(const u16x4*)(inp + base + 4*i);
    u16x4 b = *(const u16x4*)(c3  + base + 4*i);
    u16x4 c = *(const u16x4*)(c3 + MN   + base + 4*i);
    u16x4 d = *(const u16x4*)(c3 + 2*MN + base + 4*i);
    #pragma unroll
    for (int j = 0; j < 4; j++){
      iv[4*i+j] = b2f(a[j]); cv[4*i+j] = b2f(b[j]);
      mv[4*i+j] = b2f(c[j]); gv[4*i+j] = b2f(d[j]);
    }
  }
  float gmax = 0.f;
  #pragma unroll
  for (int j = 0; j < 12; j++) gmax = fmaxf(gmax, fabsf(gv[j]));
  gmax = waveMax(gmax);
  float rg = 1.f / (gmax + 1e-9f);

  float rt[12], rmax = 0.f;
  #pragma unroll
  for (int j = 0; j < 12; j++){
    rt[j] = mv[j] - fmaxf(gv[j]*rg, 0.f);
    rmax  = fmaxf(rmax, fabsf(rt[j]));
  }
  rmax = waveMax(rmax);
  float rr = 1.f / (rmax + 1e-9f);

  float val[12];
  #pragma unroll
  for (int j = 0; j < 12; j++) val[j] = (iv[j] + cv[j]) * fmaxf(rt[j]*rr, 0.f);

  if (mode == 0){
    int s = row & (S_ - 1);
    const float* cp = cosT + (size_t)s*H_ + l*12;
    const float* sp = sinT + (size_t)s*H_ + l*12;
    float o[12];
    #pragma unroll
    for (int i = 0; i < 3; i++){
      f32x4 cw = *(const f32x4*)(cp + 4*i);
      f32x4 sw = *(const f32x4*)(sp + 4*i);
      #pragma unroll
      for (int j = 0; j < 4; j++){
        int q = 4*i + j;
        float partner = __shfl_xor(val[q], 32);
        if (l < 32) partner = -partner;
        o[q] = val[q]*cw[j] + partner*sw[j];
      }
    }
    #pragma unroll
    for (int i = 0; i < 3; i++){
      u16x4 u; 
      #pragma unroll
      for (int j = 0; j < 4; j++) u[j] = f2b(o[4*i+j]);
      *(u16x4*)(outb + base + 4*i) = u;
    }
  } else if (mode == 1 || mode == 3){
    #pragma unroll
    for (int i = 0; i < 3; i++){
      u16x4 u;
      #pragma unroll
      for (int j = 0; j < 4; j++){
        float v = val[4*i+j];
        if (mode == 3) v = fmaxf(v, 0.f);
        u[j] = f2b(v);
      }
      *(u16x4*)(outb + base + 4*i) = u;
    }
  } else {
    #pragma unroll
    for (int i = 0; i < 3; i++){
      f32x4 rv = *(const f32x4*)(resid + base + 4*i);
      f32x4 ov;
      #pragma unroll
      for (int j = 0; j < 4; j++) ov[j] = val[4*i+j] + rv[j];
      *(f32x4*)(outf + base + 4*i) = ov;
    }
  }
}

// ---------------- causal softmax: bf16 scores -> bf16 P, batched over b ----------------
__global__ __launch_bounds__(256) void softmax_causal(const bf16_t* __restrict__ sc,
                                                      bf16_t* __restrict__ P){
  __shared__ float red[4];
  int r = blockIdx.x, b = blockIdx.y, t = threadIdx.x;
  const bf16_t* srow = sc + (size_t)b*SS + (size_t)r * S_;
  bf16_t* prow = P + (size_t)b*SS + (size_t)r * S_;
  int n = r + 1;
  int fill = ((r >> 7) + 1) << 7;          // PV reads k < row0+128; zero up to there
  float m = -1e30f;
  for (int j = t; j < n; j += 256) m = fmaxf(m, (float)srow[j]);
  m = blockReduce<true>(m, red);
  float sum = 0.f;
  for (int j = t; j < n; j += 256) sum += __expf((float)srow[j] - m);
  sum = blockReduce<false>(sum, red);
  float inv = 1.f / sum;
  for (int j = t; j < fill; j += 256)
    prow[j] = (j < n) ? (bf16_t)(__expf((float)srow[j] - m)*inv) : (bf16_t)0.f;
}

// ---------------- 32x32 tiled transpose [B,S,H] -> [B,H,S] ----------------
__global__ __launch_bounds__(256) void transpose_bf(const bf16_t* __restrict__ in,
                                                    bf16_t* __restrict__ out){
  __shared__ bf16_t tile[32][33];
  int bz = blockIdx.z;
  const bf16_t* I = in  + (size_t)bz * SH;
  bf16_t*       O = out + (size_t)bz * SH;
  int s0 = blockIdx.x*32, h0 = blockIdx.y*32;
  int tx = threadIdx.x, ty = threadIdx.y;
  #pragma unroll
  for (int k = 0; k < 4; k++)
    tile[ty + 8*k][tx] = I[(size_t)(s0 + ty + 8*k)*H_ + h0 + tx];
  __syncthreads();
  #pragma unroll
  for (int k = 0; k < 4; k++)
    O[(size_t)(h0 + ty + 8*k)*S_ + s0 + tx] = tile[tx][ty + 8*k];
}

// ---------------- launch ----------------
extern "C" void kernel_launch(void* const* d_in, const int* in_sizes, int n_in,
                              void* d_out, int out_size, void* d_ws, size_t ws_size,
                              hipStream_t stream){
  const float* x    = (const float*)d_in[0];
  const float* cosT = (const float*)d_in[1];
  const float* sinT = (const float*)d_in[2];
  const float* ln1w = (const float*)d_in[3];
  const float* ln1b = (const float*)d_in[4];
  const float* ln2w = (const float*)d_in[5];
  const float* ln2b = (const float*)d_in[6];

  W18 wp; const float* bias[6];
  for (int i = 0; i < 6; i++){
    const float* proto = (const float*)d_in[7 + 4*i + 0];
    const float* gatep = (const float*)d_in[7 + 4*i + 1];
    const float* muw   = (const float*)d_in[7 + 4*i + 2];
    bias[i]            = (const float*)d_in[7 + 4*i + 3];
    wp.p[i*3 + 0] = muw;    // z=0: comp
    wp.p[i*3 + 1] = proto;  // z=1: match
    wp.p[i*3 + 2] = gatep;  // z=2: gate
  }

  hipFuncSetAttribute((const void*)gemm256, hipFuncAttributeMaxDynamicSharedMemorySize, 131072);

  char* w = (char*)d_ws;
  auto alloc = [&](size_t bytes){ void* r = (void*)w; w += (bytes + 255) & ~(size_t)255; return r; };
  bf16_t* w_bf   = (bf16_t*)alloc((size_t)18 * HH * 2);
  bf16_t* a_bf   = (bf16_t*)alloc(MN * 2);
  bf16_t* h_bf   = (bf16_t*)alloc(MN * 2);
  bf16_t* c3b    = (bf16_t*)alloc(3 * MN * 2);
  bf16_t* q_bf   = (bf16_t*)alloc(MN * 2);
  bf16_t* k_bf   = (bf16_t*)alloc(MN * 2);
  bf16_t* v_bf   = (bf16_t*)alloc(MN * 2);
  bf16_t* vt     = (bf16_t*)alloc(MN * 2);
  bf16_t* sc_bf  = (bf16_t*)alloc(B_ * SS * 2);
  bf16_t* p_bf   = (bf16_t*)alloc(B_ * SS * 2);
  bf16_t* attn_b = (bf16_t*)alloc(MN * 2);
  float*  x1     = (float*) alloc(MN * 4);
  (void)ws_size;

  const float rs = 1.0f / sqrtf((float)H_);

  conv_weights<<<dim3(HH/1024, 18), 256, 0, stream>>>(wp, w_bf);
  ln_kernel<<<M_, 256, 0, stream>>>(x, ln1w, ln1b, a_bf);

  bf16_t* qkv[3] = {q_bf, k_bf, v_bf};
  for (int s = 0; s < 3; s++){
    gemm256<<<dim3(H_/256, M_/256, 3), 512, 131072, stream>>>(
        a_bf, w_bf + (size_t)s*3*HH, c3b, M_, H_, H_,
        0, (long)HH, (long)MN, 1.f, rs, 1.f, bias[s], 0);
    gate_kernel<<<M_/4, 256, 0, stream>>>(a_bf, c3b, cosT, sinT, nullptr, nullptr, qkv[s], (s < 2) ? 0 : 1);
  }

  transpose_bf<<<dim3(S_/32, H_/32, B_), dim3(32, 8), 0, stream>>>(v_bf, vt);

  // QK^T, all batches (causal 256-tile skip)
  gemm256<<<dim3(S_/256, S_/256, B_), 512, 131072, stream>>>(
      q_bf, k_bf, sc_bf, S_, S_, H_,
      (long)SH, (long)SH, (long)SS, rs, rs, rs, nullptr, 1);

  softmax_causal<<<dim3(S_, B_), 256, 0, stream>>>(sc_bf, p_bf);

  // PV, all batches (K limited causally) — 128^2 kernel
  gemm_bt<<<dim3(H_/128, S_/128, B_), 256, 0, stream>>>(
      p_bf, vt, attn_b, S_, H_, S_,
      (long)SS, (long)SH, (long)SH, 1.f, 1.f, 1.f, nullptr, 2);

  // o-SPL + gate(+residual x) -> x1
  gemm256<<<dim3(H_/256, M_/256, 3), 512, 131072, stream>>>(
      attn_b, w_bf + (size_t)9*HH, c3b, M_, H_, H_, 0, (long)HH, (long)MN, 1.f, rs, 1.f, bias[3], 0);
  gate_kernel<<<M_/4, 256, 0, stream>>>(attn_b, c3b, nullptr, nullptr, x, x1, nullptr, 2);

  // LN2
  ln_kernel<<<M_, 256, 0, stream>>>(x1, ln2w, ln2b, a_bf);

  // f1-SPL + gate + relu -> h_bf
  gemm256<<<dim3(H_/256, M_/256, 3), 512, 131072, stream>>>(
      a_bf, w_bf + (size_t)12*HH, c3b, M_, H_, H_, 0, (long)HH, (long)MN, 1.f, rs, 1.f, bias[4], 0);
  gate_kernel<<<M_/4, 256, 0, stream>>>(a_bf, c3b, nullptr, nullptr, nullptr, nullptr, h_bf, 3);

  // f2-SPL + gate(+residual x1) -> d_out
  gemm256<<<dim3(H_/256, M_/256, 3), 512, 131072, stream>>>(
      h_bf, w_bf + (size_t)15*HH, c3b, M_, H_, H_, 0, (long)HH, (long)MN, 1.f, rs, 1.f, bias[5], 0);
  gate_kernel<<<M_/4, 256, 0, stream>>>(h_bf, c3b, nullptr, nullptr, x1, (float*)d_out, nullptr, 2);
}

// Round 4
// 536.630 us; speedup vs baseline: 1.0251x; 1.0251x over previous
//
#include <hip/hip_runtime.h>
#include <hip/hip_bf16.h>
#include <math.h>

#define B_ 4
#define S_ 2048
#define H_ 768
#define M_ (B_*S_)                 // 8192 rows
#define MN ((size_t)M_*(size_t)H_) // 6291456
#define HH (H_*H_)                 // 589824
#define SS ((size_t)S_*(size_t)S_)
#define SH ((size_t)S_*(size_t)H_)

typedef __bf16 bf16_t;
typedef __bf16 bf16x8 __attribute__((ext_vector_type(8)));
typedef __bf16 bf16x4 __attribute__((ext_vector_type(4)));
typedef float  f32x4  __attribute__((ext_vector_type(4)));
typedef unsigned short u16;
typedef u16 u16x4 __attribute__((ext_vector_type(4)));

typedef __attribute__((address_space(3))) void       lds_void_t;
typedef __attribute__((address_space(1))) const void gvoid_t;

__device__ __forceinline__ float b2f(u16 u){ unsigned x = (unsigned)u << 16; float f; __builtin_memcpy(&f,&x,4); return f; }
__device__ __forceinline__ u16 f2b(float f){ bf16_t h = (bf16_t)f; u16 u; __builtin_memcpy(&u,&h,2); return u; }

// ---------------- block reduction helper (blockDim == 256) ----------------
template<bool MAXOP>
__device__ __forceinline__ float blockReduce(float v, float* s){
  #pragma unroll
  for (int o = 32; o; o >>= 1){
    float t = __shfl_xor(v, o);
    v = MAXOP ? fmaxf(v, t) : (v + t);
  }
  int lane = threadIdx.x & 63, w = threadIdx.x >> 6;
  if (lane == 0) s[w] = v;
  __syncthreads();
  float r = s[0];
  #pragma unroll
  for (int i = 1; i < 4; i++) r = MAXOP ? fmaxf(r, s[i]) : (r + s[i]);
  __syncthreads();
  return r;
}

__device__ __forceinline__ float waveMax(float v){
  #pragma unroll
  for (int o = 1; o < 64; o <<= 1) v = fmaxf(v, __shfl_xor(v, o));
  return v;
}

// ---------------- weight conversion fp32 -> bf16 (x4 vectorized) ----------------
struct W18 { const float* p[18]; };

__global__ __launch_bounds__(256) void conv_weights(W18 w, bf16_t* __restrict__ out){
  int m = blockIdx.y;
  int i = (blockIdx.x * 256 + threadIdx.x) * 4;   // grid.x*1024 == HH exactly
  f32x4 v = *(const f32x4*)(w.p[m] + i);
  bf16x4 o; o[0]=(bf16_t)v[0]; o[1]=(bf16_t)v[1]; o[2]=(bf16_t)v[2]; o[3]=(bf16_t)v[3];
  *(bf16x4*)(out + (size_t)m * HH + i) = o;
}

// ---------------- LayerNorm: bf16 out ----------------
__global__ __launch_bounds__(256) void ln_kernel(const float* __restrict__ x,
                                                 const float* __restrict__ w,
                                                 const float* __restrict__ b,
                                                 bf16_t* __restrict__ outb){
  __shared__ float red[4];
  int row = blockIdx.x, t = threadIdx.x;
  size_t base = (size_t)row * H_;
  float v[3]; float sum = 0.f, sq = 0.f;
  #pragma unroll
  for (int i = 0; i < 3; i++){
    v[i] = x[base + t + i*256];
    sum += v[i]; sq += v[i]*v[i];
  }
  sum = blockReduce<false>(sum, red);
  sq  = blockReduce<false>(sq,  red);
  float mu  = sum * (1.f/H_);
  float var = sq  * (1.f/H_) - mu*mu;
  float rstd = rsqrtf(var + 1e-5f);
  #pragma unroll
  for (int i = 0; i < 3; i++){
    int j = t + i*256;
    outb[base+j] = (bf16_t)((v[i]-mu)*rstd*w[j] + b[j]);
  }
}

// ======================================================================
// 256x256 / BK=64 / 8-wave 2-PHASE GEMM: C = A * B^T (bf16 in/out)
// one STAGE + one vmcnt(0) + one barrier per K-tile (proven m248/m230
// structure); XOR-swizzled LDS reads with pre-swizzled global source.
// ======================================================================
__global__ __launch_bounds__(512, 2) void gemm256(const bf16_t* __restrict__ A,
                                                  const bf16_t* __restrict__ Bm,
                                                  bf16_t* __restrict__ C,
                                                  int M, int N, int K,
                                                  long sA, long sB, long sC,
                                                  float scale0, float scale1, float scale2,
                                                  const float* __restrict__ bias0, int causal){
  extern __shared__ char smem[];   // 128 KiB: A[2][256*64] | B[2][256*64]
  char* Abase = smem;
  char* Bbase = smem + 65536;

  // bijective XCD swizzle over flat id (nwg % 8 == 0 for all our grids)
  int gx = gridDim.x, gy = gridDim.y;
  int nwg = gx * gy * gridDim.z;
  int id  = (blockIdx.z * gy + blockIdx.y) * gx + blockIdx.x;
  int sid = (id & 7) * (nwg >> 3) + (id >> 3);
  int bx  = sid % gx;
  int by  = (sid / gx) % gy;
  int z   = sid / (gx * gy);

  A  += (size_t)z * sA;
  Bm += (size_t)z * sB;
  C  += (size_t)z * sC;
  float scale = (z==0) ? scale0 : (z==1) ? scale1 : scale2;
  const float* bias = (z==0) ? bias0 : nullptr;

  int row0 = by * 256, col0 = bx * 256;
  if (causal && col0 > row0) return;

  int tid  = threadIdx.x;
  int lane = tid & 63, wid = tid >> 6;
  int wm = wid >> 2, wn = wid & 3;        // 2x4 wave grid; wave block 128x64
  int lr = lane & 15, kg = lane >> 4;

  int NT = K >> 6;                         // BK = 64

  // staging: A-tile 256x64x2B = 32KB = 2048 16B-chunks; 512 thr x 4 chunks.
  // chunk c = tid + i*512: row r = c>>3, 16B slot cb = c&7.
  int r0s = tid >> 3, cbs = tid & 7;
  int ecol = (cbs ^ (r0s & 7)) * 8;        // swizzled source col (bf16 elems)

  auto stage = [&](int buf, int kt){
    const bf16_t* srcA = A  + (size_t)(row0 + r0s) * K + kt*64 + ecol;
    const bf16_t* srcB = Bm + (size_t)(col0 + r0s) * K + kt*64 + ecol;
    char* dstA = Abase + buf*32768 + r0s*128 + cbs*16;
    char* dstB = Bbase + buf*32768 + r0s*128 + cbs*16;
    #pragma unroll
    for (int i = 0; i < 4; i++){
      __builtin_amdgcn_global_load_lds((gvoid_t*)(srcA + (size_t)(i*64)*K), (lds_void_t*)(dstA + i*64*128), 16, 0, 0);
      __builtin_amdgcn_global_load_lds((gvoid_t*)(srcB + (size_t)(i*64)*K), (lds_void_t*)(dstB + i*64*128), 16, 0, 0);
    }
  };
  auto rdA = [&](int buf, int r, int s) -> bf16x8 {
    int off = r*128 + ((s*64 + kg*16) ^ ((r & 7) << 4));
    return *(const bf16x8*)(Abase + buf*32768 + off);
  };
  auto rdB = [&](int buf, int r, int s) -> bf16x8 {
    int off = r*128 + ((s*64 + kg*16) ^ ((r & 7) << 4));
    return *(const bf16x8*)(Bbase + buf*32768 + off);
  };

  f32x4 acc[8][4] = {};

  stage(0, 0);
  asm volatile("s_waitcnt vmcnt(0)" ::: "memory");
  __builtin_amdgcn_s_barrier();

  int buf = 0;
  for (int t = 0; t < NT; ++t){
    if (t + 1 < NT) stage(buf ^ 1, t + 1);      // issue next-tile loads FIRST
    bf16x8 a0[8], a1[8], b0[4], b1[4];
    #pragma unroll
    for (int m = 0; m < 8; m++){ a0[m] = rdA(buf, wm*128 + m*16 + lr, 0);
                                 a1[m] = rdA(buf, wm*128 + m*16 + lr, 1); }
    #pragma unroll
    for (int n = 0; n < 4; n++){ b0[n] = rdB(buf, wn*64 + n*16 + lr, 0);
                                 b1[n] = rdB(buf, wn*64 + n*16 + lr, 1); }
    #pragma unroll
    for (int m = 0; m < 8; m++)
      #pragma unroll
      for (int n = 0; n < 4; n++){
        acc[m][n] = __builtin_amdgcn_mfma_f32_16x16x32_bf16(a0[m], b0[n], acc[m][n], 0,0,0);
        acc[m][n] = __builtin_amdgcn_mfma_f32_16x16x32_bf16(a1[m], b1[n], acc[m][n], 0,0,0);
      }
    if (t + 1 < NT) asm volatile("s_waitcnt vmcnt(0)" ::: "memory");
    __builtin_amdgcn_s_barrier();
    buf ^= 1;
  }

  // epilogue: C/D layout col=lane&15, row=(lane>>4)*4+reg
  #pragma unroll
  for (int m = 0; m < 8; m++){
    int rb = row0 + wm*128 + m*16 + kg*4;
    #pragma unroll
    for (int n = 0; n < 4; n++){
      int cc = col0 + wn*64 + n*16 + lr;
      float bv = bias ? bias[cc] : 0.f;
      #pragma unroll
      for (int r = 0; r < 4; r++)
        C[(size_t)(rb + r)*N + cc] = (bf16_t)(acc[m][n][r]*scale + bv);
    }
  }
}

// ---------------- 128x128 GEMM (QK^T + PV) ----------------
__global__ __launch_bounds__(256) void gemm_bt(const bf16_t* __restrict__ A,
                                               const bf16_t* __restrict__ Bm,
                                               bf16_t* __restrict__ C,
                                               int M, int N, int K,
                                               long sA, long sB, long sC,
                                               float scale0, float scale1, float scale2,
                                               const float* __restrict__ bias0, int cmode){
  int gx = gridDim.x, gy = gridDim.y;
  int nwg = gx * gy * gridDim.z;
  int id  = (blockIdx.z * gy + blockIdx.y) * gx + blockIdx.x;
  int sid = (id & 7) * (nwg >> 3) + (id >> 3);
  int bx  = sid % gx;
  int by  = (sid / gx) % gy;
  int z   = sid / (gx * gy);

  A  += (size_t)z * sA;
  Bm += (size_t)z * sB;
  C  += (size_t)z * sC;
  float scale = (z==0) ? scale0 : (z==1) ? scale1 : scale2;
  const float* bias = (z==0) ? bias0 : nullptr;

  int row0 = by * 128, col0 = bx * 128;
  if (cmode == 1 && col0 > row0) return;

  __shared__ bf16_t As[2][128*32];
  __shared__ bf16_t Bs[2][128*32];

  int tid  = threadIdx.x;
  int lane = tid & 63;
  int wave = tid >> 6;
  int wm = wave >> 1, wn = wave & 1;
  int lr = lane & 15, kg = lane >> 4;

  f32x4 acc[4][4] = {};
  int NT = K >> 5;
  if (cmode == 2) { int lim = (row0 + 128) >> 5; NT = NT < lim ? NT : lim; }

  auto stage = [&](int buf, int kt){
    int kk = kt * 32;
    #pragma unroll
    for (int i = 0; i < 2; i++){
      int c  = tid + i*256;
      int r  = c >> 2;
      int c8 = (c & 3) * 8;
      __builtin_amdgcn_global_load_lds((gvoid_t*)(A  + (size_t)(row0 + r)*K + kk + c8),
                                       (lds_void_t*)(&As[buf][c*8]), 16, 0, 0);
      __builtin_amdgcn_global_load_lds((gvoid_t*)(Bm + (size_t)(col0 + r)*K + kk + c8),
                                       (lds_void_t*)(&Bs[buf][c*8]), 16, 0, 0);
    }
  };

  stage(0, 0);
  __syncthreads();
  int buf = 0;
  for (int kt = 0; kt < NT; ++kt){
    if (kt + 1 < NT) stage(buf ^ 1, kt + 1);
    bf16x8 af[4], bfr[4];
    #pragma unroll
    for (int m = 0; m < 4; m++)
      af[m] = *reinterpret_cast<const bf16x8*>(&As[buf][(wm*64 + m*16 + lr)*32 + kg*8]);
    #pragma unroll
    for (int n = 0; n < 4; n++)
      bfr[n] = *reinterpret_cast<const bf16x8*>(&Bs[buf][(wn*64 + n*16 + lr)*32 + kg*8]);
    #pragma unroll
    for (int m = 0; m < 4; m++)
      #pragma unroll
      for (int n = 0; n < 4; n++)
        acc[m][n] = __builtin_amdgcn_mfma_f32_16x16x32_bf16(af[m], bfr[n], acc[m][n], 0, 0, 0);
    __syncthreads();
    buf ^= 1;
  }

  #pragma unroll
  for (int m = 0; m < 4; m++){
    int rb = row0 + wm*64 + m*16 + kg*4;
    #pragma unroll
    for (int n = 0; n < 4; n++){
      int cc = col0 + wn*64 + n*16 + lr;
      float bv = bias ? bias[cc] : 0.f;
      #pragma unroll
      for (int r = 0; r < 4; r++)
        C[(size_t)(rb + r)*N + cc] = (bf16_t)(acc[m][n][r]*scale + bv);
    }
  }
}

// ---------------- gate branch: wave-per-row, vectorized ----------------
// mode 0: rope -> outb ; mode 1: plain -> outb ; mode 2: +resid -> outf ; mode 3: relu -> outb
__global__ __launch_bounds__(256) void gate_kernel(const bf16_t* __restrict__ inp,
                                                   const bf16_t* __restrict__ c3,
                                                   const float* __restrict__ cosT,
                                                   const float* __restrict__ sinT,
                                                   const float* __restrict__ resid,
                                                   float* __restrict__ outf,
                                                   bf16_t* __restrict__ outb,
                                                   int mode){
  int wid = threadIdx.x >> 6, l = threadIdx.x & 63;
  int row = blockIdx.x * 4 + wid;
  size_t base = (size_t)row * H_ + l*12;

  float iv[12], cv[12], mv[12], gv[12];
  #pragma unroll
  for (int i = 0; i < 3; i++){
    u16x4 a = *(const u16x4*)(inp + base + 4*i);
    u16x4 b = *(const u16x4*)(c3  + base + 4*i);
    u16x4 c = *(const u16x4*)(c3 + MN   + base + 4*i);
    u16x4 d = *(const u16x4*)(c3 + 2*MN + base + 4*i);
    #pragma unroll
    for (int j = 0; j < 4; j++){
      iv[4*i+j] = b2f(a[j]); cv[4*i+j] = b2f(b[j]);
      mv[4*i+j] = b2f(c[j]); gv[4*i+j] = b2f(d[j]);
    }
  }
  float gmax = 0.f;
  #pragma unroll
  for (int j = 0; j < 12; j++) gmax = fmaxf(gmax, fabsf(gv[j]));
  gmax = waveMax(gmax);
  float rg = 1.f / (gmax + 1e-9f);

  float rt[12], rmax = 0.f;
  #pragma unroll
  for (int j = 0; j < 12; j++){
    rt[j] = mv[j] - fmaxf(gv[j]*rg, 0.f);
    rmax  = fmaxf(rmax, fabsf(rt[j]));
  }
  rmax = waveMax(rmax);
  float rr = 1.f / (rmax + 1e-9f);

  float val[12];
  #pragma unroll
  for (int j = 0; j < 12; j++) val[j] = (iv[j] + cv[j]) * fmaxf(rt[j]*rr, 0.f);

  if (mode == 0){
    int s = row & (S_ - 1);
    const float* cp = cosT + (size_t)s*H_ + l*12;
    const float* sp = sinT + (size_t)s*H_ + l*12;
    float o[12];
    #pragma unroll
    for (int i = 0; i < 3; i++){
      f32x4 cw = *(const f32x4*)(cp + 4*i);
      f32x4 sw = *(const f32x4*)(sp + 4*i);
      #pragma unroll
      for (int j = 0; j < 4; j++){
        int q = 4*i + j;
        float partner = __shfl_xor(val[q], 32);
        if (l < 32) partner = -partner;
        o[q] = val[q]*cw[j] + partner*sw[j];
      }
    }
    #pragma unroll
    for (int i = 0; i < 3; i++){
      u16x4 u;
      #pragma unroll
      for (int j = 0; j < 4; j++) u[j] = f2b(o[4*i+j]);
      *(u16x4*)(outb + base + 4*i) = u;
    }
  } else if (mode == 1 || mode == 3){
    #pragma unroll
    for (int i = 0; i < 3; i++){
      u16x4 u;
      #pragma unroll
      for (int j = 0; j < 4; j++){
        float v = val[4*i+j];
        if (mode == 3) v = fmaxf(v, 0.f);
        u[j] = f2b(v);
      }
      *(u16x4*)(outb + base + 4*i) = u;
    }
  } else {
    #pragma unroll
    for (int i = 0; i < 3; i++){
      f32x4 rv = *(const f32x4*)(resid + base + 4*i);
      f32x4 ov;
      #pragma unroll
      for (int j = 0; j < 4; j++) ov[j] = val[4*i+j] + rv[j];
      *(f32x4*)(outf + base + 4*i) = ov;
    }
  }
}

// ---------------- causal softmax: bf16 scores -> bf16 P, batched over b ----------------
__global__ __launch_bounds__(256) void softmax_causal(const bf16_t* __restrict__ sc,
                                                      bf16_t* __restrict__ P){
  __shared__ float red[4];
  int r = blockIdx.x, b = blockIdx.y, t = threadIdx.x;
  const bf16_t* srow = sc + (size_t)b*SS + (size_t)r * S_;
  bf16_t* prow = P + (size_t)b*SS + (size_t)r * S_;
  int n = r + 1;
  int fill = ((r >> 7) + 1) << 7;          // PV reads k < row0+128; zero up to there
  float m = -1e30f;
  for (int j = t; j < n; j += 256) m = fmaxf(m, (float)srow[j]);
  m = blockReduce<true>(m, red);
  float sum = 0.f;
  for (int j = t; j < n; j += 256) sum += __expf((float)srow[j] - m);
  sum = blockReduce<false>(sum, red);
  float inv = 1.f / sum;
  for (int j = t; j < fill; j += 256)
    prow[j] = (j < n) ? (bf16_t)(__expf((float)srow[j] - m)*inv) : (bf16_t)0.f;
}

// ---------------- 32x32 tiled transpose [B,S,H] -> [B,H,S] ----------------
__global__ __launch_bounds__(256) void transpose_bf(const bf16_t* __restrict__ in,
                                                    bf16_t* __restrict__ out){
  __shared__ bf16_t tile[32][33];
  int bz = blockIdx.z;
  const bf16_t* I = in  + (size_t)bz * SH;
  bf16_t*       O = out + (size_t)bz * SH;
  int s0 = blockIdx.x*32, h0 = blockIdx.y*32;
  int tx = threadIdx.x, ty = threadIdx.y;
  #pragma unroll
  for (int k = 0; k < 4; k++)
    tile[ty + 8*k][tx] = I[(size_t)(s0 + ty + 8*k)*H_ + h0 + tx];
  __syncthreads();
  #pragma unroll
  for (int k = 0; k < 4; k++)
    O[(size_t)(h0 + ty + 8*k)*S_ + s0 + tx] = tile[tx][ty + 8*k];
}

// ---------------- launch ----------------
extern "C" void kernel_launch(void* const* d_in, const int* in_sizes, int n_in,
                              void* d_out, int out_size, void* d_ws, size_t ws_size,
                              hipStream_t stream){
  const float* x    = (const float*)d_in[0];
  const float* cosT = (const float*)d_in[1];
  const float* sinT = (const float*)d_in[2];
  const float* ln1w = (const float*)d_in[3];
  const float* ln1b = (const float*)d_in[4];
  const float* ln2w = (const float*)d_in[5];
  const float* ln2b = (const float*)d_in[6];

  W18 wp; const float* bias[6];
  for (int i = 0; i < 6; i++){
    const float* proto = (const float*)d_in[7 + 4*i + 0];
    const float* gatep = (const float*)d_in[7 + 4*i + 1];
    const float* muw   = (const float*)d_in[7 + 4*i + 2];
    bias[i]            = (const float*)d_in[7 + 4*i + 3];
    wp.p[i*3 + 0] = muw;    // z=0: comp
    wp.p[i*3 + 1] = proto;  // z=1: match
    wp.p[i*3 + 2] = gatep;  // z=2: gate
  }

  hipFuncSetAttribute((const void*)gemm256, hipFuncAttributeMaxDynamicSharedMemorySize, 131072);

  char* w = (char*)d_ws;
  auto alloc = [&](size_t bytes){ void* r = (void*)w; w += (bytes + 255) & ~(size_t)255; return r; };
  bf16_t* w_bf   = (bf16_t*)alloc((size_t)18 * HH * 2);
  bf16_t* a_bf   = (bf16_t*)alloc(MN * 2);
  bf16_t* h_bf   = (bf16_t*)alloc(MN * 2);
  bf16_t* c3b    = (bf16_t*)alloc(3 * MN * 2);
  bf16_t* q_bf   = (bf16_t*)alloc(MN * 2);
  bf16_t* k_bf   = (bf16_t*)alloc(MN * 2);
  bf16_t* v_bf   = (bf16_t*)alloc(MN * 2);
  bf16_t* vt     = (bf16_t*)alloc(MN * 2);
  bf16_t* sc_bf  = (bf16_t*)alloc(B_ * SS * 2);
  bf16_t* p_bf   = (bf16_t*)alloc(B_ * SS * 2);
  bf16_t* attn_b = (bf16_t*)alloc(MN * 2);
  float*  x1     = (float*) alloc(MN * 4);
  (void)ws_size;

  const float rs = 1.0f / sqrtf((float)H_);

  conv_weights<<<dim3(HH/1024, 18), 256, 0, stream>>>(wp, w_bf);
  ln_kernel<<<M_, 256, 0, stream>>>(x, ln1w, ln1b, a_bf);

  bf16_t* qkv[3] = {q_bf, k_bf, v_bf};
  for (int s = 0; s < 3; s++){
    gemm256<<<dim3(H_/256, M_/256, 3), 512, 131072, stream>>>(
        a_bf, w_bf + (size_t)s*3*HH, c3b, M_, H_, H_,
        0, (long)HH, (long)MN, 1.f, rs, 1.f, bias[s], 0);
    gate_kernel<<<M_/4, 256, 0, stream>>>(a_bf, c3b, cosT, sinT, nullptr, nullptr, qkv[s], (s < 2) ? 0 : 1);
  }

  transpose_bf<<<dim3(S_/32, H_/32, B_), dim3(32, 8), 0, stream>>>(v_bf, vt);

  // QK^T, all batches (causal 128-tile skip) — 128^2 kernel, 1024-block grid
  gemm_bt<<<dim3(S_/128, S_/128, B_), 256, 0, stream>>>(
      q_bf, k_bf, sc_bf, S_, S_, H_,
      (long)SH, (long)SH, (long)SS, rs, rs, rs, nullptr, 1);

  softmax_causal<<<dim3(S_, B_), 256, 0, stream>>>(sc_bf, p_bf);

  // PV, all batches (K limited causally) — 128^2 kernel
  gemm_bt<<<dim3(H_/128, S_/128, B_), 256, 0, stream>>>(
      p_bf, vt, attn_b, S_, H_, S_,
      (long)SS, (long)SH, (long)SH, 1.f, 1.f, 1.f, nullptr, 2);

  // o-SPL + gate(+residual x) -> x1
  gemm256<<<dim3(H_/256, M_/256, 3), 512, 131072, stream>>>(
      attn_b, w_bf + (size_t)9*HH, c3b, M_, H_, H_, 0, (long)HH, (long)MN, 1.f, rs, 1.f, bias[3], 0);
  gate_kernel<<<M_/4, 256, 0, stream>>>(attn_b, c3b, nullptr, nullptr, x, x1, nullptr, 2);

  // LN2
  ln_kernel<<<M_, 256, 0, stream>>>(x1, ln2w, ln2b, a_bf);

  // f1-SPL + gate + relu -> h_bf
  gemm256<<<dim3(H_/256, M_/256, 3), 512, 131072, stream>>>(
      a_bf, w_bf + (size_t)12*HH, c3b, M_, H_, H_, 0, (long)HH, (long)MN, 1.f, rs, 1.f, bias[4], 0);
  gate_kernel<<<M_/4, 256, 0, stream>>>(a_bf, c3b, nullptr, nullptr, nullptr, nullptr, h_bf, 3);

  // f2-SPL + gate(+residual x1) -> d_out
  gemm256<<<dim3(H_/256, M_/256, 3), 512, 131072, stream>>>(
      h_bf, w_bf + (size_t)15*HH, c3b, M_, H_, H_, 0, (long)HH, (long)MN, 1.f, rs, 1.f, bias[5], 0);
  gate_kernel<<<M_/4, 256, 0, stream>>>(h_bf, c3b, nullptr, nullptr, x1, (float*)d_out, nullptr, 2);
}

// Round 5
// 488.029 us; speedup vs baseline: 1.1272x; 1.0996x over previous
//
#include <hip/hip_runtime.h>
#include <hip/hip_bf16.h>
#include <math.h>

#define B_ 4
#define S_ 2048
#define H_ 768
#define M_ (B_*S_)                 // 8192 rows
#define MN ((size_t)M_*(size_t)H_) // 6291456
#define HH (H_*H_)                 // 589824
#define SS ((size_t)S_*(size_t)S_)
#define SH ((size_t)S_*(size_t)H_)
#define NQKV 6912                  // 9 fused weight matrices
#define N3   2304                  // 3 fused weight matrices

typedef __bf16 bf16_t;
typedef __bf16 bf16x8 __attribute__((ext_vector_type(8)));
typedef __bf16 bf16x4 __attribute__((ext_vector_type(4)));
typedef float  f32x4  __attribute__((ext_vector_type(4)));
typedef unsigned short u16;
typedef u16 u16x4 __attribute__((ext_vector_type(4)));

typedef __attribute__((address_space(3))) void       lds_void_t;
typedef __attribute__((address_space(1))) const void gvoid_t;

__device__ __forceinline__ float b2f(u16 u){ unsigned x = (unsigned)u << 16; float f; __builtin_memcpy(&f,&x,4); return f; }
__device__ __forceinline__ u16 f2b(float f){ bf16_t h = (bf16_t)f; u16 u; __builtin_memcpy(&u,&h,2); return u; }

template<bool MAXOP>
__device__ __forceinline__ float blockReduce(float v, float* s){
  #pragma unroll
  for (int o = 32; o; o >>= 1){
    float t = __shfl_xor(v, o);
    v = MAXOP ? fmaxf(v, t) : (v + t);
  }
  int lane = threadIdx.x & 63, w = threadIdx.x >> 6;
  if (lane == 0) s[w] = v;
  __syncthreads();
  float r = s[0];
  #pragma unroll
  for (int i = 1; i < 4; i++) r = MAXOP ? fmaxf(r, s[i]) : (r + s[i]);
  __syncthreads();
  return r;
}

__device__ __forceinline__ float waveMax(float v){
  #pragma unroll
  for (int o = 1; o < 64; o <<= 1) v = fmaxf(v, __shfl_xor(v, o));
  return v;
}
__device__ __forceinline__ float waveSum(float v){
  #pragma unroll
  for (int o = 1; o < 64; o <<= 1) v += __shfl_xor(v, o);
  return v;
}

// ---------------- weight conversion fp32 -> bf16; match (proto) plane scaled by 1/sqrt(d) ----------------
struct W18 { const float* p[18]; };

__global__ __launch_bounds__(256) void conv_weights(W18 w, bf16_t* __restrict__ out, float rs){
  int m = blockIdx.y;
  float sc = (m % 3 == 1) ? rs : 1.0f;
  int i = (blockIdx.x * 256 + threadIdx.x) * 4;   // grid.x*1024 == HH exactly
  f32x4 v = *(const f32x4*)(w.p[m] + i);
  bf16x4 o; o[0]=(bf16_t)(v[0]*sc); o[1]=(bf16_t)(v[1]*sc); o[2]=(bf16_t)(v[2]*sc); o[3]=(bf16_t)(v[3]*sc);
  *(bf16x4*)(out + (size_t)m * HH + i) = o;
}

// ---------------- LayerNorm (wave-per-row): fp32 in -> bf16 out ----------------
__global__ __launch_bounds__(256) void ln_kernel(const float* __restrict__ x,
                                                 const float* __restrict__ w,
                                                 const float* __restrict__ b,
                                                 bf16_t* __restrict__ outb){
  int wid = threadIdx.x >> 6, l = threadIdx.x & 63;
  int row = blockIdx.x * 4 + wid;
  size_t base = (size_t)row * H_ + l*12;
  float v[12];
  #pragma unroll
  for (int i = 0; i < 3; i++){
    f32x4 t = *(const f32x4*)(x + base + 4*i);
    #pragma unroll
    for (int j = 0; j < 4; j++) v[4*i+j] = t[j];
  }
  float s1 = 0.f, s2 = 0.f;
  #pragma unroll
  for (int j = 0; j < 12; j++){ s1 += v[j]; s2 += v[j]*v[j]; }
  s1 = waveSum(s1); s2 = waveSum(s2);
  float mu = s1 * (1.f/H_), var = s2 * (1.f/H_) - mu*mu;
  float rstd = rsqrtf(var + 1e-5f);
  #pragma unroll
  for (int i = 0; i < 3; i++){
    f32x4 wv = *(const f32x4*)(w + l*12 + 4*i);
    f32x4 bv = *(const f32x4*)(b + l*12 + 4*i);
    u16x4 u;
    #pragma unroll
    for (int j = 0; j < 4; j++) u[j] = f2b((v[4*i+j]-mu)*rstd*wv[j] + bv[j]);
    *(u16x4*)(outb + base + 4*i) = u;
  }
}

// ======================================================================
// 128x128 GEMM, ring-3 LDS, counted vmcnt, XOR-swizzled LDS (rule 21).
// C = A * B^T (bf16 in/out, no scale/bias). cmode: 0 none, 1 causal
// tile-skip, 2 causal K-limit. NT must be >= 2 (K >= 64).
// ======================================================================
__global__ __launch_bounds__(256) void gemm_bt(const bf16_t* __restrict__ A,
                                               const bf16_t* __restrict__ Bm,
                                               bf16_t* __restrict__ C,
                                               int M, int N, int K,
                                               long sA, long sB, long sC, int cmode){
  __shared__ bf16_t As[3][128*32];
  __shared__ bf16_t Bs[3][128*32];

  // bijective XCD swizzle over flat id (nwg % 8 == 0 for all our grids)
  int gx = gridDim.x, gy = gridDim.y;
  int nwg = gx * gy * gridDim.z;
  int id  = (blockIdx.z * gy + blockIdx.y) * gx + blockIdx.x;
  int sid = (id & 7) * (nwg >> 3) + (id >> 3);
  int bx  = sid % gx;
  int by  = (sid / gx) % gy;
  int z   = sid / (gx * gy);

  A  += (size_t)z * sA;
  Bm += (size_t)z * sB;
  C  += (size_t)z * sC;

  int row0 = by * 128, col0 = bx * 128;
  if (cmode == 1 && col0 > row0) return;

  int tid  = threadIdx.x;
  int lane = tid & 63;
  int wave = tid >> 6;
  int wm = wave >> 1, wn = wave & 1;    // 2x2 waves, 64x64 out each
  int lr = lane & 15, kg = lane >> 4;

  f32x4 acc[4][4] = {};
  int NT = K >> 5;                       // BK = 32
  if (cmode == 2) { int lim = (row0 + 128) >> 5; NT = NT < lim ? NT : lim; }

  // stage: 128 rows x 32 cols = 512 x 16B chunks; 256 thr x 2.
  // chunk-in-row j is XOR-swizzled with (row&3) on BOTH source and read.
  auto stage = [&](int buf, int kt){
    int kk = kt * 32;
    #pragma unroll
    for (int i = 0; i < 2; i++){
      int c  = tid + i*256;
      int r  = c >> 2;
      int scol = ((c & 3) ^ (r & 3)) * 8;
      __builtin_amdgcn_global_load_lds((gvoid_t*)(A  + (size_t)(row0 + r)*K + kk + scol),
                                       (lds_void_t*)(&As[buf][c*8]), 16, 0, 0);
      __builtin_amdgcn_global_load_lds((gvoid_t*)(Bm + (size_t)(col0 + r)*K + kk + scol),
                                       (lds_void_t*)(&Bs[buf][c*8]), 16, 0, 0);
    }
  };

  stage(0, 0);
  stage(1, 1);                                  // NT >= 2 for all our calls
  asm volatile("s_waitcnt vmcnt(4)" ::: "memory");
  __builtin_amdgcn_s_barrier();
  __builtin_amdgcn_sched_barrier(0);

  int b0 = 0, b1 = 1, b2 = 2;
  for (int kt = 0; kt < NT; ++kt){
    if (kt + 2 < NT) stage(b2, kt + 2);
    bf16x8 af[4], bfr[4];
    #pragma unroll
    for (int m = 0; m < 4; m++){
      int r = wm*64 + m*16 + lr;
      af[m] = *reinterpret_cast<const bf16x8*>(&As[b0][r*32 + ((kg ^ (r & 3)) * 8)]);
    }
    #pragma unroll
    for (int n = 0; n < 4; n++){
      int r = wn*64 + n*16 + lr;
      bfr[n] = *reinterpret_cast<const bf16x8*>(&Bs[b0][r*32 + ((kg ^ (r & 3)) * 8)]);
    }
    #pragma unroll
    for (int m = 0; m < 4; m++)
      #pragma unroll
      for (int n = 0; n < 4; n++)
        acc[m][n] = __builtin_amdgcn_mfma_f32_16x16x32_bf16(af[m], bfr[n], acc[m][n], 0, 0, 0);
    if (kt + 1 < NT){
      if (kt + 2 < NT) asm volatile("s_waitcnt vmcnt(4)" ::: "memory");
      else             asm volatile("s_waitcnt vmcnt(0)" ::: "memory");
      __builtin_amdgcn_s_barrier();
      __builtin_amdgcn_sched_barrier(0);
    }
    int tmp = b0; b0 = b1; b1 = b2; b2 = tmp;
  }

  // epilogue: C/D layout col=lane&15, row=(lane>>4)*4+reg
  #pragma unroll
  for (int m = 0; m < 4; m++){
    int rb = row0 + wm*64 + m*16 + kg*4;
    #pragma unroll
    for (int n = 0; n < 4; n++){
      int cc = col0 + wn*64 + n*16 + lr;
      #pragma unroll
      for (int r = 0; r < 4; r++)
        C[(size_t)(rb + r)*N + cc] = (bf16_t)acc[m][n][r];
    }
  }
}

// ---------------- gate branch: wave-per-row ----------------
// c3 row layout: [comp | match | gate] at colbase+0/768/1536, row stride ldc.
// bias added to comp here. oscale multiplies gated output (q: 1/sqrt(d)).
// mode 0: rope -> outb ; 1: plain -> outb ; 2: +resid -> outf
// mode 3: relu -> outb ; 4: +resid -> outf AND LayerNorm -> outb
__global__ __launch_bounds__(256) void gate_kernel(const bf16_t* __restrict__ inp,
                                                   const bf16_t* __restrict__ c3,
                                                   long ldc, int colbase,
                                                   const float* __restrict__ bias,
                                                   const float* __restrict__ cosT,
                                                   const float* __restrict__ sinT,
                                                   const float* __restrict__ resid,
                                                   const float* __restrict__ lnw,
                                                   const float* __restrict__ lnb,
                                                   float* __restrict__ outf,
                                                   bf16_t* __restrict__ outb,
                                                   float oscale, int mode){
  int wid = threadIdx.x >> 6, l = threadIdx.x & 63;
  int row = blockIdx.x * 4 + wid;
  size_t bi = (size_t)row * H_ + l*12;
  size_t bc = (size_t)row * ldc + colbase + l*12;

  float iv[12], cv[12], mv[12], gv[12];
  float gmax = 0.f;
  #pragma unroll
  for (int i = 0; i < 3; i++){
    u16x4 a = *(const u16x4*)(inp + bi + 4*i);
    u16x4 b = *(const u16x4*)(c3 + bc + 4*i);
    u16x4 c = *(const u16x4*)(c3 + bc + 768 + 4*i);
    u16x4 d = *(const u16x4*)(c3 + bc + 1536 + 4*i);
    f32x4 bv = *(const f32x4*)(bias + l*12 + 4*i);
    #pragma unroll
    for (int j = 0; j < 4; j++){
      iv[4*i+j] = b2f(a[j]); cv[4*i+j] = b2f(b[j]) + bv[j];
      mv[4*i+j] = b2f(c[j]); gv[4*i+j] = b2f(d[j]);
      gmax = fmaxf(gmax, fabsf(gv[4*i+j]));
    }
  }
  gmax = waveMax(gmax);
  float rg = 1.f / (gmax + 1e-9f);

  float rt[12], rmax = 0.f;
  #pragma unroll
  for (int j = 0; j < 12; j++){
    rt[j] = mv[j] - fmaxf(gv[j]*rg, 0.f);
    rmax  = fmaxf(rmax, fabsf(rt[j]));
  }
  rmax = waveMax(rmax);
  float rr = 1.f / (rmax + 1e-9f);

  float val[12];
  #pragma unroll
  for (int j = 0; j < 12; j++) val[j] = (iv[j] + cv[j]) * fmaxf(rt[j]*rr, 0.f) * oscale;

  if (mode == 0){
    int s = row & (S_ - 1);
    const float* cp = cosT + (size_t)s*H_ + l*12;
    const float* sp = sinT + (size_t)s*H_ + l*12;
    #pragma unroll
    for (int i = 0; i < 3; i++){
      f32x4 cw = *(const f32x4*)(cp + 4*i);
      f32x4 sw = *(const f32x4*)(sp + 4*i);
      u16x4 u;
      #pragma unroll
      for (int j = 0; j < 4; j++){
        int q = 4*i + j;
        float partner = __shfl_xor(val[q], 32);
        if (l < 32) partner = -partner;
        u[j] = f2b(val[q]*cw[j] + partner*sw[j]);
      }
      *(u16x4*)(outb + bi + 4*i) = u;
    }
  } else if (mode == 1 || mode == 3){
    #pragma unroll
    for (int i = 0; i < 3; i++){
      u16x4 u;
      #pragma unroll
      for (int j = 0; j < 4; j++){
        float v = val[4*i+j];
        if (mode == 3) v = fmaxf(v, 0.f);
        u[j] = f2b(v);
      }
      *(u16x4*)(outb + bi + 4*i) = u;
    }
  } else if (mode == 2){
    #pragma unroll
    for (int i = 0; i < 3; i++){
      f32x4 rv = *(const f32x4*)(resid + bi + 4*i);
      f32x4 ov;
      #pragma unroll
      for (int j = 0; j < 4; j++) ov[j] = val[4*i+j] + rv[j];
      *(f32x4*)(outf + bi + 4*i) = ov;
    }
  } else { // mode 4: residual + write x1 + fused LayerNorm -> outb
    float xv[12];
    #pragma unroll
    for (int i = 0; i < 3; i++){
      f32x4 rv = *(const f32x4*)(resid + bi + 4*i);
      f32x4 ov;
      #pragma unroll
      for (int j = 0; j < 4; j++){ xv[4*i+j] = val[4*i+j] + rv[j]; ov[j] = xv[4*i+j]; }
      *(f32x4*)(outf + bi + 4*i) = ov;
    }
    float s1 = 0.f, s2 = 0.f;
    #pragma unroll
    for (int j = 0; j < 12; j++){ s1 += xv[j]; s2 += xv[j]*xv[j]; }
    s1 = waveSum(s1); s2 = waveSum(s2);
    float mu = s1 * (1.f/H_), var = s2 * (1.f/H_) - mu*mu;
    float rstd = rsqrtf(var + 1e-5f);
    #pragma unroll
    for (int i = 0; i < 3; i++){
      f32x4 wv = *(const f32x4*)(lnw + l*12 + 4*i);
      f32x4 bv = *(const f32x4*)(lnb + l*12 + 4*i);
      u16x4 u;
      #pragma unroll
      for (int j = 0; j < 4; j++) u[j] = f2b((xv[4*i+j]-mu)*rstd*wv[j] + bv[j]);
      *(u16x4*)(outb + bi + 4*i) = u;
    }
  }
}

// ---------------- causal softmax: bf16 scores -> bf16 P, batched over b ----------------
__global__ __launch_bounds__(256) void softmax_causal(const bf16_t* __restrict__ sc,
                                                      bf16_t* __restrict__ P){
  __shared__ float red[4];
  int r = blockIdx.x, b = blockIdx.y, t = threadIdx.x;
  const bf16_t* srow = sc + (size_t)b*SS + (size_t)r * S_;
  bf16_t* prow = P + (size_t)b*SS + (size_t)r * S_;
  int n = r + 1;
  int fill = ((r >> 7) + 1) << 7;          // PV reads k < row0+128; zero up to there
  float m = -1e30f;
  for (int j = t; j < n; j += 256) m = fmaxf(m, (float)srow[j]);
  m = blockReduce<true>(m, red);
  float sum = 0.f;
  for (int j = t; j < n; j += 256) sum += __expf((float)srow[j] - m);
  sum = blockReduce<false>(sum, red);
  float inv = 1.f / sum;
  for (int j = t; j < fill; j += 256)
    prow[j] = (j < n) ? (bf16_t)(__expf((float)srow[j] - m)*inv) : (bf16_t)0.f;
}

// ---------------- 32x32 tiled transpose [B,S,H] -> [B,H,S] ----------------
__global__ __launch_bounds__(256) void transpose_bf(const bf16_t* __restrict__ in,
                                                    bf16_t* __restrict__ out){
  __shared__ bf16_t tile[32][33];
  int bz = blockIdx.z;
  const bf16_t* I = in  + (size_t)bz * SH;
  bf16_t*       O = out + (size_t)bz * SH;
  int s0 = blockIdx.x*32, h0 = blockIdx.y*32;
  int tx = threadIdx.x, ty = threadIdx.y;
  #pragma unroll
  for (int k = 0; k < 4; k++)
    tile[ty + 8*k][tx] = I[(size_t)(s0 + ty + 8*k)*H_ + h0 + tx];
  __syncthreads();
  #pragma unroll
  for (int k = 0; k < 4; k++)
    O[(size_t)(h0 + ty + 8*k)*S_ + s0 + tx] = tile[tx][ty + 8*k];
}

// ---------------- launch ----------------
extern "C" void kernel_launch(void* const* d_in, const int* in_sizes, int n_in,
                              void* d_out, int out_size, void* d_ws, size_t ws_size,
                              hipStream_t stream){
  const float* x    = (const float*)d_in[0];
  const float* cosT = (const float*)d_in[1];
  const float* sinT = (const float*)d_in[2];
  const float* ln1w = (const float*)d_in[3];
  const float* ln1b = (const float*)d_in[4];
  const float* ln2w = (const float*)d_in[5];
  const float* ln2b = (const float*)d_in[6];

  W18 wp; const float* bias[6];
  for (int i = 0; i < 6; i++){
    const float* proto = (const float*)d_in[7 + 4*i + 0];
    const float* gatep = (const float*)d_in[7 + 4*i + 1];
    const float* muw   = (const float*)d_in[7 + 4*i + 2];
    bias[i]            = (const float*)d_in[7 + 4*i + 3];
    wp.p[i*3 + 0] = muw;    // comp
    wp.p[i*3 + 1] = proto;  // match (scaled by rs at conversion)
    wp.p[i*3 + 2] = gatep;  // gate
  }

  char* w = (char*)d_ws;
  auto alloc = [&](size_t bytes){ void* r = (void*)w; w += (bytes + 255) & ~(size_t)255; return r; };
  bf16_t* w_bf   = (bf16_t*)alloc((size_t)18 * HH * 2);      // [13824, 768]
  bf16_t* a_bf   = (bf16_t*)alloc(MN * 2);                   // activation
  bf16_t* h_bf   = (bf16_t*)alloc(MN * 2);                   // relu hidden
  bf16_t* c3b    = (bf16_t*)alloc((size_t)M_ * NQKV * 2);    // logits (max width); also holds scores+P
  bf16_t* q_bf   = (bf16_t*)alloc(MN * 2);
  bf16_t* k_bf   = (bf16_t*)alloc(MN * 2);
  bf16_t* v_bf   = (bf16_t*)alloc(MN * 2);
  bf16_t* vt     = (bf16_t*)alloc(MN * 2);
  bf16_t* attn_b = (bf16_t*)alloc(MN * 2);
  float*  x1     = (float*) alloc(MN * 4);
  (void)ws_size;
  bf16_t* sc_bf = c3b;                  // overlay: c3b free during attention
  bf16_t* p_bf  = c3b + B_ * SS;

  const float rs = 1.0f / sqrtf((float)H_);

  conv_weights<<<dim3(HH/1024, 18), 256, 0, stream>>>(wp, w_bf, rs);
  ln_kernel<<<M_/4, 256, 0, stream>>>(x, ln1w, ln1b, a_bf);

  // QKV fused SPL: c3b[M, 6912]
  gemm_bt<<<dim3(NQKV/128, M_/128, 1), 256, 0, stream>>>(
      a_bf, w_bf, c3b, M_, NQKV, H_, 0, 0, 0, 0);
  gate_kernel<<<M_/4, 256, 0, stream>>>(a_bf, c3b, NQKV, 0,    bias[0], cosT, sinT, nullptr, nullptr, nullptr, nullptr, q_bf, rs,  0);
  gate_kernel<<<M_/4, 256, 0, stream>>>(a_bf, c3b, NQKV, 2304, bias[1], cosT, sinT, nullptr, nullptr, nullptr, nullptr, k_bf, 1.f, 0);
  gate_kernel<<<M_/4, 256, 0, stream>>>(a_bf, c3b, NQKV, 4608, bias[2], nullptr, nullptr, nullptr, nullptr, nullptr, nullptr, v_bf, 1.f, 1);

  transpose_bf<<<dim3(S_/32, H_/32, B_), dim3(32, 8), 0, stream>>>(v_bf, vt);

  // QK^T (scores scale folded into q), causal tile-skip
  gemm_bt<<<dim3(S_/128, S_/128, B_), 256, 0, stream>>>(
      q_bf, k_bf, sc_bf, S_, S_, H_, (long)SH, (long)SH, (long)SS, 1);

  softmax_causal<<<dim3(S_, B_), 256, 0, stream>>>(sc_bf, p_bf);

  // PV (K limited causally)
  gemm_bt<<<dim3(H_/128, S_/128, B_), 256, 0, stream>>>(
      p_bf, vt, attn_b, S_, H_, S_, (long)SS, (long)SH, (long)SH, 2);

  // o-SPL + gate(+residual x) + fused LN2 -> x1 (f32) and a_bf (LN2 out)
  gemm_bt<<<dim3(N3/128, M_/128, 1), 256, 0, stream>>>(
      attn_b, w_bf + (size_t)9*HH, c3b, M_, N3, H_, 0, 0, 0, 0);
  gate_kernel<<<M_/4, 256, 0, stream>>>(attn_b, c3b, N3, 0, bias[3], nullptr, nullptr, x, ln2w, ln2b, x1, a_bf, 1.f, 4);

  // f1-SPL + gate + relu -> h_bf
  gemm_bt<<<dim3(N3/128, M_/128, 1), 256, 0, stream>>>(
      a_bf, w_bf + (size_t)12*HH, c3b, M_, N3, H_, 0, 0, 0, 0);
  gate_kernel<<<M_/4, 256, 0, stream>>>(a_bf, c3b, N3, 0, bias[4], nullptr, nullptr, nullptr, nullptr, nullptr, nullptr, h_bf, 1.f, 3);

  // f2-SPL + gate(+residual x1) -> d_out
  gemm_bt<<<dim3(N3/128, M_/128, 1), 256, 0, stream>>>(
      h_bf, w_bf + (size_t)15*HH, c3b, M_, N3, H_, 0, 0, 0, 0);
  gate_kernel<<<M_/4, 256, 0, stream>>>(h_bf, c3b, N3, 0, bias[5], nullptr, nullptr, x1, nullptr, nullptr, (float*)d_out, nullptr, 1.f, 2);
}

// Round 6
// 470.623 us; speedup vs baseline: 1.1689x; 1.0370x over previous
//
#include <hip/hip_runtime.h>
#include <hip/hip_bf16.h>
#include <math.h>

#define B_ 4
#define S_ 2048
#define H_ 768
#define M_ (B_*S_)                 // 8192 rows
#define MN ((size_t)M_*(size_t)H_) // 6291456
#define HH (H_*H_)                 // 589824
#define SS ((size_t)S_*(size_t)S_)
#define SH ((size_t)S_*(size_t)H_)
#define NQKV 6912                  // 9 fused weight matrices
#define N3   2304                  // 3 fused weight matrices

typedef __bf16 bf16_t;
typedef __bf16 bf16x8 __attribute__((ext_vector_type(8)));
typedef __bf16 bf16x4 __attribute__((ext_vector_type(4)));
typedef float  f32x4  __attribute__((ext_vector_type(4)));
typedef unsigned short u16;
typedef u16 u16x4 __attribute__((ext_vector_type(4)));

typedef __attribute__((address_space(3))) void       lds_void_t;
typedef __attribute__((address_space(1))) const void gvoid_t;

__device__ __forceinline__ float b2f(u16 u){ unsigned x = (unsigned)u << 16; float f; __builtin_memcpy(&f,&x,4); return f; }
__device__ __forceinline__ u16 f2b(float f){ bf16_t h = (bf16_t)f; u16 u; __builtin_memcpy(&u,&h,2); return u; }

template<bool MAXOP>
__device__ __forceinline__ float blockReduce(float v, float* s){
  #pragma unroll
  for (int o = 32; o; o >>= 1){
    float t = __shfl_xor(v, o);
    v = MAXOP ? fmaxf(v, t) : (v + t);
  }
  int lane = threadIdx.x & 63, w = threadIdx.x >> 6;
  if (lane == 0) s[w] = v;
  __syncthreads();
  float r = s[0];
  #pragma unroll
  for (int i = 1; i < 4; i++) r = MAXOP ? fmaxf(r, s[i]) : (r + s[i]);
  __syncthreads();
  return r;
}

__device__ __forceinline__ float waveMax(float v){
  #pragma unroll
  for (int o = 1; o < 64; o <<= 1) v = fmaxf(v, __shfl_xor(v, o));
  return v;
}
__device__ __forceinline__ float waveSum(float v){
  #pragma unroll
  for (int o = 1; o < 64; o <<= 1) v += __shfl_xor(v, o);
  return v;
}

// ---------------- weight conversion fp32 -> bf16; match (proto) plane scaled by 1/sqrt(d) ----------------
struct W18 { const float* p[18]; };

__global__ __launch_bounds__(256) void conv_weights(W18 w, bf16_t* __restrict__ out, float rs){
  int m = blockIdx.y;
  float sc = (m % 3 == 1) ? rs : 1.0f;
  int i = (blockIdx.x * 256 + threadIdx.x) * 4;   // grid.x*1024 == HH exactly
  f32x4 v = *(const f32x4*)(w.p[m] + i);
  bf16x4 o; o[0]=(bf16_t)(v[0]*sc); o[1]=(bf16_t)(v[1]*sc); o[2]=(bf16_t)(v[2]*sc); o[3]=(bf16_t)(v[3]*sc);
  *(bf16x4*)(out + (size_t)m * HH + i) = o;
}

// ---------------- LayerNorm (wave-per-row): fp32 in -> bf16 out ----------------
__global__ __launch_bounds__(256) void ln_kernel(const float* __restrict__ x,
                                                 const float* __restrict__ w,
                                                 const float* __restrict__ b,
                                                 bf16_t* __restrict__ outb){
  int wid = threadIdx.x >> 6, l = threadIdx.x & 63;
  int row = blockIdx.x * 4 + wid;
  size_t base = (size_t)row * H_ + l*12;
  float v[12];
  #pragma unroll
  for (int i = 0; i < 3; i++){
    f32x4 t = *(const f32x4*)(x + base + 4*i);
    #pragma unroll
    for (int j = 0; j < 4; j++) v[4*i+j] = t[j];
  }
  float s1 = 0.f, s2 = 0.f;
  #pragma unroll
  for (int j = 0; j < 12; j++){ s1 += v[j]; s2 += v[j]*v[j]; }
  s1 = waveSum(s1); s2 = waveSum(s2);
  float mu = s1 * (1.f/H_), var = s2 * (1.f/H_) - mu*mu;
  float rstd = rsqrtf(var + 1e-5f);
  #pragma unroll
  for (int i = 0; i < 3; i++){
    f32x4 wv = *(const f32x4*)(w + l*12 + 4*i);
    f32x4 bv = *(const f32x4*)(b + l*12 + 4*i);
    u16x4 u;
    #pragma unroll
    for (int j = 0; j < 4; j++) u[j] = f2b((v[4*i+j]-mu)*rstd*wv[j] + bv[j]);
    *(u16x4*)(outb + base + 4*i) = u;
  }
}

// ======================================================================
// 128x128 GEMM, ring-3 LDS, counted vmcnt, XOR-swizzled LDS.
// Swizzle (r>>1)&3: 16-lane read group covers 8 distinct bank positions
// at 2 lanes each (m136 free regime). Block order: column-major within
// each XCD's 8-row band (A-band L2-resident, B fetched once per XCD).
// C = A * B^T (bf16 in/out). cmode: 0 none, 1 causal tile-skip,
// 2 causal K-limit. NT must be >= 2 (K >= 64).
// ======================================================================
__global__ __launch_bounds__(256) void gemm_bt(const bf16_t* __restrict__ A,
                                               const bf16_t* __restrict__ Bm,
                                               bf16_t* __restrict__ C,
                                               int M, int N, int K,
                                               long sA, long sB, long sC, int cmode){
  __shared__ bf16_t As[3][128*32];
  __shared__ bf16_t Bs[3][128*32];

  // XCD-banded, column-major-in-band block mapping.
  // Requires nwg%8==0 and (nwg/8)%gridDim.x==0 (true for all our grids).
  int gx = gridDim.x, gy = gridDim.y;
  int nwg = gx * gy * gridDim.z;
  int id  = (blockIdx.z * gy + blockIdx.y) * gx + blockIdx.x;
  int cpx = nwg >> 3;            // blocks per XCD
  int nrb = cpx / gx;            // row-panels per XCD band
  int x   = id & 7;              // XCD (round-robin dispatch assumption)
  int local = id >> 3;
  int bx  = local / nrb;
  int frow = x * nrb + (local % nrb);
  int by  = frow % gy;
  int z   = frow / gy;

  A  += (size_t)z * sA;
  Bm += (size_t)z * sB;
  C  += (size_t)z * sC;

  int row0 = by * 128, col0 = bx * 128;
  if (cmode == 1 && col0 > row0) return;

  int tid  = threadIdx.x;
  int lane = tid & 63;
  int wave = tid >> 6;
  int wm = wave >> 1, wn = wave & 1;    // 2x2 waves, 64x64 out each
  int lr = lane & 15, kg = lane >> 4;

  f32x4 acc[4][4] = {};
  int NT = K >> 5;                       // BK = 32
  if (cmode == 2) { int lim = (row0 + 128) >> 5; NT = NT < lim ? NT : lim; }

  // stage: 128 rows x 32 cols = 512 x 16B chunks; 256 thr x 2.
  // chunk slot j in row r holds global chunk j ^ ((r>>1)&3)  (rule 21:
  // same involution on source col and read).
  auto stage = [&](int buf, int kt){
    int kk = kt * 32;
    #pragma unroll
    for (int i = 0; i < 2; i++){
      int c  = tid + i*256;
      int r  = c >> 2;
      int scol = ((c & 3) ^ ((r >> 1) & 3)) * 8;
      __builtin_amdgcn_global_load_lds((gvoid_t*)(A  + (size_t)(row0 + r)*K + kk + scol),
                                       (lds_void_t*)(&As[buf][c*8]), 16, 0, 0);
      __builtin_amdgcn_global_load_lds((gvoid_t*)(Bm + (size_t)(col0 + r)*K + kk + scol),
                                       (lds_void_t*)(&Bs[buf][c*8]), 16, 0, 0);
    }
  };

  stage(0, 0);
  stage(1, 1);                                  // NT >= 2 for all our calls
  asm volatile("s_waitcnt vmcnt(4)" ::: "memory");
  __builtin_amdgcn_s_barrier();
  __builtin_amdgcn_sched_barrier(0);

  int b0 = 0, b1 = 1, b2 = 2;
  for (int kt = 0; kt < NT; ++kt){
    if (kt + 2 < NT) stage(b2, kt + 2);
    bf16x8 af[4], bfr[4];
    #pragma unroll
    for (int m = 0; m < 4; m++){
      int r = wm*64 + m*16 + lr;
      af[m] = *reinterpret_cast<const bf16x8*>(&As[b0][r*32 + ((kg ^ ((r >> 1) & 3)) * 8)]);
    }
    #pragma unroll
    for (int n = 0; n < 4; n++){
      int r = wn*64 + n*16 + lr;
      bfr[n] = *reinterpret_cast<const bf16x8*>(&Bs[b0][r*32 + ((kg ^ ((r >> 1) & 3)) * 8)]);
    }
    #pragma unroll
    for (int m = 0; m < 4; m++)
      #pragma unroll
      for (int n = 0; n < 4; n++)
        acc[m][n] = __builtin_amdgcn_mfma_f32_16x16x32_bf16(af[m], bfr[n], acc[m][n], 0, 0, 0);
    if (kt + 1 < NT){
      if (kt + 2 < NT) asm volatile("s_waitcnt vmcnt(4)" ::: "memory");
      else             asm volatile("s_waitcnt vmcnt(0)" ::: "memory");
      __builtin_amdgcn_s_barrier();
      __builtin_amdgcn_sched_barrier(0);
    }
    int tmp = b0; b0 = b1; b1 = b2; b2 = tmp;
  }

  // epilogue: C/D layout col=lane&15, row=(lane>>4)*4+reg
  #pragma unroll
  for (int m = 0; m < 4; m++){
    int rb = row0 + wm*64 + m*16 + kg*4;
    #pragma unroll
    for (int n = 0; n < 4; n++){
      int cc = col0 + wn*64 + n*16 + lr;
      #pragma unroll
      for (int r = 0; r < 4; r++)
        C[(size_t)(rb + r)*N + cc] = (bf16_t)acc[m][n][r];
    }
  }
}

// ---------------- gate branch: wave-per-row ----------------
// c3 row layout: [comp | match | gate] at colbase+0/768/1536, row stride ldc.
// bias added to comp here. oscale multiplies gated output (q: 1/sqrt(d)).
// mode 0: rope -> outb ; 1: plain -> outb ; 2: +resid -> outf
// mode 3: relu -> outb ; 4: +resid -> outf AND LayerNorm -> outb
__global__ __launch_bounds__(256) void gate_kernel(const bf16_t* __restrict__ inp,
                                                   const bf16_t* __restrict__ c3,
                                                   long ldc, int colbase,
                                                   const float* __restrict__ bias,
                                                   const float* __restrict__ cosT,
                                                   const float* __restrict__ sinT,
                                                   const float* __restrict__ resid,
                                                   const float* __restrict__ lnw,
                                                   const float* __restrict__ lnb,
                                                   float* __restrict__ outf,
                                                   bf16_t* __restrict__ outb,
                                                   float oscale, int mode){
  int wid = threadIdx.x >> 6, l = threadIdx.x & 63;
  int row = blockIdx.x * 4 + wid;
  size_t bi = (size_t)row * H_ + l*12;
  size_t bc = (size_t)row * ldc + colbase + l*12;

  float iv[12], cv[12], mv[12], gv[12];
  float gmax = 0.f;
  #pragma unroll
  for (int i = 0; i < 3; i++){
    u16x4 a = *(const u16x4*)(inp + bi + 4*i);
    u16x4 b = *(const u16x4*)(c3 + bc + 4*i);
    u16x4 c = *(const u16x4*)(c3 + bc + 768 + 4*i);
    u16x4 d = *(const u16x4*)(c3 + bc + 1536 + 4*i);
    f32x4 bv = *(const f32x4*)(bias + l*12 + 4*i);
    #pragma unroll
    for (int j = 0; j < 4; j++){
      iv[4*i+j] = b2f(a[j]); cv[4*i+j] = b2f(b[j]) + bv[j];
      mv[4*i+j] = b2f(c[j]); gv[4*i+j] = b2f(d[j]);
      gmax = fmaxf(gmax, fabsf(gv[4*i+j]));
    }
  }
  gmax = waveMax(gmax);
  float rg = 1.f / (gmax + 1e-9f);

  float rt[12], rmax = 0.f;
  #pragma unroll
  for (int j = 0; j < 12; j++){
    rt[j] = mv[j] - fmaxf(gv[j]*rg, 0.f);
    rmax  = fmaxf(rmax, fabsf(rt[j]));
  }
  rmax = waveMax(rmax);
  float rr = 1.f / (rmax + 1e-9f);

  float val[12];
  #pragma unroll
  for (int j = 0; j < 12; j++) val[j] = (iv[j] + cv[j]) * fmaxf(rt[j]*rr, 0.f) * oscale;

  if (mode == 0){
    int s = row & (S_ - 1);
    const float* cp = cosT + (size_t)s*H_ + l*12;
    const float* sp = sinT + (size_t)s*H_ + l*12;
    #pragma unroll
    for (int i = 0; i < 3; i++){
      f32x4 cw = *(const f32x4*)(cp + 4*i);
      f32x4 sw = *(const f32x4*)(sp + 4*i);
      u16x4 u;
      #pragma unroll
      for (int j = 0; j < 4; j++){
        int q = 4*i + j;
        float partner = __shfl_xor(val[q], 32);
        if (l < 32) partner = -partner;
        u[j] = f2b(val[q]*cw[j] + partner*sw[j]);
      }
      *(u16x4*)(outb + bi + 4*i) = u;
    }
  } else if (mode == 1 || mode == 3){
    #pragma unroll
    for (int i = 0; i < 3; i++){
      u16x4 u;
      #pragma unroll
      for (int j = 0; j < 4; j++){
        float v = val[4*i+j];
        if (mode == 3) v = fmaxf(v, 0.f);
        u[j] = f2b(v);
      }
      *(u16x4*)(outb + bi + 4*i) = u;
    }
  } else if (mode == 2){
    #pragma unroll
    for (int i = 0; i < 3; i++){
      f32x4 rv = *(const f32x4*)(resid + bi + 4*i);
      f32x4 ov;
      #pragma unroll
      for (int j = 0; j < 4; j++) ov[j] = val[4*i+j] + rv[j];
      *(f32x4*)(outf + bi + 4*i) = ov;
    }
  } else { // mode 4: residual + write x1 + fused LayerNorm -> outb
    float xv[12];
    #pragma unroll
    for (int i = 0; i < 3; i++){
      f32x4 rv = *(const f32x4*)(resid + bi + 4*i);
      f32x4 ov;
      #pragma unroll
      for (int j = 0; j < 4; j++){ xv[4*i+j] = val[4*i+j] + rv[j]; ov[j] = xv[4*i+j]; }
      *(f32x4*)(outf + bi + 4*i) = ov;
    }
    float s1 = 0.f, s2 = 0.f;
    #pragma unroll
    for (int j = 0; j < 12; j++){ s1 += xv[j]; s2 += xv[j]*xv[j]; }
    s1 = waveSum(s1); s2 = waveSum(s2);
    float mu = s1 * (1.f/H_), var = s2 * (1.f/H_) - mu*mu;
    float rstd = rsqrtf(var + 1e-5f);
    #pragma unroll
    for (int i = 0; i < 3; i++){
      f32x4 wv = *(const f32x4*)(lnw + l*12 + 4*i);
      f32x4 bv = *(const f32x4*)(lnb + l*12 + 4*i);
      u16x4 u;
      #pragma unroll
      for (int j = 0; j < 4; j++) u[j] = f2b((xv[4*i+j]-mu)*rstd*wv[j] + bv[j]);
      *(u16x4*)(outb + bi + 4*i) = u;
    }
  }
}

// ---------------- causal softmax: bf16 scores -> bf16 P, batched over b ----------------
__global__ __launch_bounds__(256) void softmax_causal(const bf16_t* __restrict__ sc,
                                                      bf16_t* __restrict__ P){
  __shared__ float red[4];
  int r = blockIdx.x, b = blockIdx.y, t = threadIdx.x;
  const bf16_t* srow = sc + (size_t)b*SS + (size_t)r * S_;
  bf16_t* prow = P + (size_t)b*SS + (size_t)r * S_;
  int n = r + 1;
  int fill = ((r >> 7) + 1) << 7;          // PV reads k < row0+128; zero up to there
  float m = -1e30f;
  for (int j = t; j < n; j += 256) m = fmaxf(m, (float)srow[j]);
  m = blockReduce<true>(m, red);
  float sum = 0.f;
  for (int j = t; j < n; j += 256) sum += __expf((float)srow[j] - m);
  sum = blockReduce<false>(sum, red);
  float inv = 1.f / sum;
  for (int j = t; j < fill; j += 256)
    prow[j] = (j < n) ? (bf16_t)(__expf((float)srow[j] - m)*inv) : (bf16_t)0.f;
}

// ---------------- 32x32 tiled transpose [B,S,H] -> [B,H,S] ----------------
__global__ __launch_bounds__(256) void transpose_bf(const bf16_t* __restrict__ in,
                                                    bf16_t* __restrict__ out){
  __shared__ bf16_t tile[32][33];
  int bz = blockIdx.z;
  const bf16_t* I = in  + (size_t)bz * SH;
  bf16_t*       O = out + (size_t)bz * SH;
  int s0 = blockIdx.x*32, h0 = blockIdx.y*32;
  int tx = threadIdx.x, ty = threadIdx.y;
  #pragma unroll
  for (int k = 0; k < 4; k++)
    tile[ty + 8*k][tx] = I[(size_t)(s0 + ty + 8*k)*H_ + h0 + tx];
  __syncthreads();
  #pragma unroll
  for (int k = 0; k < 4; k++)
    O[(size_t)(h0 + ty + 8*k)*S_ + s0 + tx] = tile[tx][ty + 8*k];
}

// ---------------- launch ----------------
extern "C" void kernel_launch(void* const* d_in, const int* in_sizes, int n_in,
                              void* d_out, int out_size, void* d_ws, size_t ws_size,
                              hipStream_t stream){
  const float* x    = (const float*)d_in[0];
  const float* cosT = (const float*)d_in[1];
  const float* sinT = (const float*)d_in[2];
  const float* ln1w = (const float*)d_in[3];
  const float* ln1b = (const float*)d_in[4];
  const float* ln2w = (const float*)d_in[5];
  const float* ln2b = (const float*)d_in[6];

  W18 wp; const float* bias[6];
  for (int i = 0; i < 6; i++){
    const float* proto = (const float*)d_in[7 + 4*i + 0];
    const float* gatep = (const float*)d_in[7 + 4*i + 1];
    const float* muw   = (const float*)d_in[7 + 4*i + 2];
    bias[i]            = (const float*)d_in[7 + 4*i + 3];
    wp.p[i*3 + 0] = muw;    // comp
    wp.p[i*3 + 1] = proto;  // match (scaled by rs at conversion)
    wp.p[i*3 + 2] = gatep;  // gate
  }

  char* w = (char*)d_ws;
  auto alloc = [&](size_t bytes){ void* r = (void*)w; w += (bytes + 255) & ~(size_t)255; return r; };
  bf16_t* w_bf   = (bf16_t*)alloc((size_t)18 * HH * 2);      // [13824, 768]
  bf16_t* a_bf   = (bf16_t*)alloc(MN * 2);                   // activation
  bf16_t* h_bf   = (bf16_t*)alloc(MN * 2);                   // relu hidden
  bf16_t* c3b    = (bf16_t*)alloc((size_t)M_ * NQKV * 2);    // logits (max width); also holds scores+P
  bf16_t* q_bf   = (bf16_t*)alloc(MN * 2);
  bf16_t* k_bf   = (bf16_t*)alloc(MN * 2);
  bf16_t* v_bf   = (bf16_t*)alloc(MN * 2);
  bf16_t* vt     = (bf16_t*)alloc(MN * 2);
  bf16_t* attn_b = (bf16_t*)alloc(MN * 2);
  float*  x1     = (float*) alloc(MN * 4);
  (void)ws_size;
  bf16_t* sc_bf = c3b;                  // overlay: c3b free during attention
  bf16_t* p_bf  = c3b + B_ * SS;

  const float rs = 1.0f / sqrtf((float)H_);

  conv_weights<<<dim3(HH/1024, 18), 256, 0, stream>>>(wp, w_bf, rs);
  ln_kernel<<<M_/4, 256, 0, stream>>>(x, ln1w, ln1b, a_bf);

  // QKV fused SPL: c3b[M, 6912]
  gemm_bt<<<dim3(NQKV/128, M_/128, 1), 256, 0, stream>>>(
      a_bf, w_bf, c3b, M_, NQKV, H_, 0, 0, 0, 0);
  gate_kernel<<<M_/4, 256, 0, stream>>>(a_bf, c3b, NQKV, 0,    bias[0], cosT, sinT, nullptr, nullptr, nullptr, nullptr, q_bf, rs,  0);
  gate_kernel<<<M_/4, 256, 0, stream>>>(a_bf, c3b, NQKV, 2304, bias[1], cosT, sinT, nullptr, nullptr, nullptr, nullptr, k_bf, 1.f, 0);
  gate_kernel<<<M_/4, 256, 0, stream>>>(a_bf, c3b, NQKV, 4608, bias[2], nullptr, nullptr, nullptr, nullptr, nullptr, nullptr, v_bf, 1.f, 1);

  transpose_bf<<<dim3(S_/32, H_/32, B_), dim3(32, 8), 0, stream>>>(v_bf, vt);

  // QK^T (scores scale folded into q), causal tile-skip
  gemm_bt<<<dim3(S_/128, S_/128, B_), 256, 0, stream>>>(
      q_bf, k_bf, sc_bf, S_, S_, H_, (long)SH, (long)SH, (long)SS, 1);

  softmax_causal<<<dim3(S_, B_), 256, 0, stream>>>(sc_bf, p_bf);

  // PV (K limited causally)
  gemm_bt<<<dim3(H_/128, S_/128, B_), 256, 0, stream>>>(
      p_bf, vt, attn_b, S_, H_, S_, (long)SS, (long)SH, (long)SH, 2);

  // o-SPL + gate(+residual x) + fused LN2 -> x1 (f32) and a_bf (LN2 out)
  gemm_bt<<<dim3(N3/128, M_/128, 1), 256, 0, stream>>>(
      attn_b, w_bf + (size_t)9*HH, c3b, M_, N3, H_, 0, 0, 0, 0);
  gate_kernel<<<M_/4, 256, 0, stream>>>(attn_b, c3b, N3, 0, bias[3], nullptr, nullptr, x, ln2w, ln2b, x1, a_bf, 1.f, 4);

  // f1-SPL + gate + relu -> h_bf
  gemm_bt<<<dim3(N3/128, M_/128, 1), 256, 0, stream>>>(
      a_bf, w_bf + (size_t)12*HH, c3b, M_, N3, H_, 0, 0, 0, 0);
  gate_kernel<<<M_/4, 256, 0, stream>>>(a_bf, c3b, N3, 0, bias[4], nullptr, nullptr, nullptr, nullptr, nullptr, nullptr, h_bf, 1.f, 3);

  // f2-SPL + gate(+residual x1) -> d_out
  gemm_bt<<<dim3(N3/128, M_/128, 1), 256, 0, stream>>>(
      h_bf, w_bf + (size_t)15*HH, c3b, M_, N3, H_, 0, 0, 0, 0);
  gate_kernel<<<M_/4, 256, 0, stream>>>(h_bf, c3b, N3, 0, bias[5], nullptr, nullptr, x1, nullptr, nullptr, (float*)d_out, nullptr, 1.f, 2);
}